// Round 3
// baseline (189.077 us; speedup 1.0000x reference)
//
#include <hip/hip_runtime.h>

// PatternDetector: B rows of L=256 int32 tokens in [0, 40).
// Per row: stable-compact nonzeros -> c[0..n-1]; count adjacent ==, >, <
// and lag-2 == over valid prefix; normalize; zero rows with n <= 1.
//
// Persistent-wave version: each wave owns RPW=16 contiguous rows, prefetches
// row r+1 while processing row r. Ballot+mbcnt (VALU) for compaction
// offsets, cndmask-to-dump scatter (no exec save/restore), DPP reduction.
// 8 waves/SIMD for latency hiding. Target: HBM floor ~22 us for 128 MiB.

constexpr int L_SEQ = 256;
constexpr int WPB   = 4;            // waves per block (block = 256 threads)
constexpr int RPW   = 16;           // rows per wave
constexpr int SLICE = L_SEQ + 64;   // +64 per-lane dump slots for zero writes

__global__ __launch_bounds__(256, 8)
void pattern_kernel(const int* __restrict__ x, float* __restrict__ out, int rows)
{
    __shared__ int c_sh[WPB][2][SLICE];

    const int tid  = threadIdx.x;
    const int wave = tid >> 6;
    const int lane = tid & 63;
    const long wid = (long)blockIdx.x * WPB + wave;
    const long row0 = wid * RPW;
    if (row0 >= rows) return;

    const int4* __restrict__ p = (const int4*)x + row0 * (L_SEQ / 4) + lane;

    int4 cur = *p;   // prefetch row 0

    for (int r = 0; r < RPW; ++r) {
        const long row = row0 + r;
        if (row >= rows) break;

        // Prefetch next row while this one is processed (1 load in flight).
        int4 nxt = cur;
        if (r + 1 < RPW && row + 1 < rows) nxt = p[(r + 1) * (L_SEQ / 4)];

        const int vals[4] = { cur.x, cur.y, cur.z, cur.w };

        // Compaction offsets via ballot + mbcnt (VALU only).
        const unsigned long long m0 = __ballot(vals[0] != 0);
        const unsigned long long m1 = __ballot(vals[1] != 0);
        const unsigned long long m2 = __ballot(vals[2] != 0);
        const unsigned long long m3 = __ballot(vals[3] != 0);

        int below = 0;
        below = __builtin_amdgcn_mbcnt_hi((unsigned)(m0 >> 32),
                __builtin_amdgcn_mbcnt_lo((unsigned)m0, below));
        below = __builtin_amdgcn_mbcnt_hi((unsigned)(m1 >> 32),
                __builtin_amdgcn_mbcnt_lo((unsigned)m1, below));
        below = __builtin_amdgcn_mbcnt_hi((unsigned)(m2 >> 32),
                __builtin_amdgcn_mbcnt_lo((unsigned)m2, below));
        below = __builtin_amdgcn_mbcnt_hi((unsigned)(m3 >> 32),
                __builtin_amdgcn_mbcnt_lo((unsigned)m3, below));

        const int n = __popcll(m0) + __popcll(m1) + __popcll(m2) + __popcll(m3);

        // Scatter into this wave's double-buffered LDS slice. Zero slots go
        // to a per-lane dump word (conflict-free), avoiding exec masking.
        int* const c = c_sh[wave][r & 1];
        int pos = below;
        #pragma unroll
        for (int j = 0; j < 4; ++j) {
            const bool nz  = (vals[j] != 0);
            const int addr = nz ? pos : (L_SEQ + lane);
            c[addr] = vals[j];
            pos += nz ? 1 : 0;
        }
        // Wave-private slice: only this wave's DS ordering matters.
        __asm__ volatile("s_waitcnt lgkmcnt(0)" ::: "memory");

        // Lane l evaluates compacted positions [4l, 4l+4).
        const int base = lane * 4;
        const int4 q = ((const int4*)c)[lane];  // b128, stride-16B: conflict-free
        // c[base+4], c[base+5] live in next lane's q.x, q.y. Lane 63's
        // results are garbage but never used (guards would need n > 256).
        const int e0 = __shfl_down(q.x, 1, 64);
        const int e1 = __shfl_down(q.y, 1, 64);
        const int a0[6] = { q.x, q.y, q.z, q.w, e0, e1 };

        // Packed counters: rep | inc<<8 | dec<<16 | per<<24. Wave totals
        // per field <= 255, so no cross-field carries.
        int packed = 0;
        #pragma unroll
        for (int j = 0; j < 4; ++j) {
            const int i  = base + j;
            const int a  = a0[j];
            const int b  = a0[j + 1];
            const int c2 = a0[j + 2];
            if (i < n - 1) {
                packed += (a == b) ? 1         : 0;
                packed += (b >  a) ? (1 << 8)  : 0;
                packed += (b <  a) ? (1 << 16) : 0;
                if (i < n - 2) packed += (a == c2) ? (1 << 24) : 0;
            }
        }

        // Wave reduction on the VALU pipe via DPP; total lands in lane 63.
        int vsum = packed;
        int t;
        t = __builtin_amdgcn_update_dpp(0, vsum, 0x111, 0xF, 0xF, true); vsum += t; // row_shr:1
        t = __builtin_amdgcn_update_dpp(0, vsum, 0x112, 0xF, 0xF, true); vsum += t; // row_shr:2
        t = __builtin_amdgcn_update_dpp(0, vsum, 0x114, 0xF, 0xE, true); vsum += t; // row_shr:4
        t = __builtin_amdgcn_update_dpp(0, vsum, 0x118, 0xF, 0xC, true); vsum += t; // row_shr:8
        t = __builtin_amdgcn_update_dpp(0, vsum, 0x142, 0xA, 0xF, true); vsum += t; // row_bcast:15
        t = __builtin_amdgcn_update_dpp(0, vsum, 0x143, 0xC, 0xF, true); vsum += t; // row_bcast:31

        if (lane == 63) {
            const int rep =  vsum        & 0xFF;
            const int inc = (vsum >> 8)  & 0xFF;
            const int dec = (vsum >> 16) & 0xFF;
            const int per = (vsum >> 24) & 0xFF;
            float4 o = make_float4(0.f, 0.f, 0.f, 0.f);
            if (n > 1) {
                const float d1 = (float)(n - 1);
                o.x = (float)rep / d1;
                o.y = (float)inc / d1;
                o.z = (float)dec / d1;
                if (n >= 4) o.w = (float)per / (float)(n - 2);
            }
            ((float4*)out)[row] = o;
        }

        cur = nxt;
    }
}

extern "C" void kernel_launch(void* const* d_in, const int* in_sizes, int n_in,
                              void* d_out, int out_size, void* d_ws, size_t ws_size,
                              hipStream_t stream) {
    const int* x  = (const int*)d_in[0];
    float*    out = (float*)d_out;
    const int rows = in_sizes[0] / L_SEQ;
    const int rows_per_block = WPB * RPW;
    const int blocks = (rows + rows_per_block - 1) / rows_per_block;
    pattern_kernel<<<dim3(blocks), dim3(256), 0, stream>>>(x, out, rows);
}

// Round 4
// 181.878 us; speedup vs baseline: 1.0396x; 1.0396x over previous
//
#include <hip/hip_runtime.h>

// PatternDetector: B rows of L=256 int32 tokens in [0, 40).
// Per row: stable-compact nonzeros -> c[0..n-1]; count adjacent ==, >, <
// and lag-2 == over valid prefix; normalize; zero rows with n <= 1.
// One wave (64 lanes) per row, massively oversubscribed grid (32768 blocks).
// Ballot+mbcnt (VALU) for compaction offsets, LDS only for scatter/gather,
// DPP add-reduction (VALU). Kernel is HBM-read-bound (~20 us for 128 MiB);
// measured dur_us is dominated by harness reset traffic (~160 us fixed).

constexpr int L_SEQ = 256;
constexpr int WPB   = 4;   // waves per block (block = 256 threads)

__global__ __launch_bounds__(256, 4)
void pattern_kernel(const int* __restrict__ x, float* __restrict__ out, int rows)
{
    __shared__ int c_sh[WPB][L_SEQ];

    const int tid  = threadIdx.x;
    const int wave = tid >> 6;
    const int lane = tid & 63;
    const int row  = blockIdx.x * WPB + wave;
    const bool valid_row = (row < rows);
    const int  rr  = valid_row ? row : 0;

    // 1) One coalesced int4 per lane: the wave reads the entire 1 KiB row.
    const int4 v = ((const int4*)(x + (size_t)rr * L_SEQ))[lane];
    int vals[4] = { v.x, v.y, v.z, v.w };

    // 2) Compaction offsets via ballot + mbcnt (no DS-pipe traffic).
    unsigned long long m0 = __ballot(vals[0] != 0);
    unsigned long long m1 = __ballot(vals[1] != 0);
    unsigned long long m2 = __ballot(vals[2] != 0);
    unsigned long long m3 = __ballot(vals[3] != 0);

    int below = 0;
    below = __builtin_amdgcn_mbcnt_hi((unsigned)(m0 >> 32),
            __builtin_amdgcn_mbcnt_lo((unsigned)m0, below));
    below = __builtin_amdgcn_mbcnt_hi((unsigned)(m1 >> 32),
            __builtin_amdgcn_mbcnt_lo((unsigned)m1, below));
    below = __builtin_amdgcn_mbcnt_hi((unsigned)(m2 >> 32),
            __builtin_amdgcn_mbcnt_lo((unsigned)m2, below));
    below = __builtin_amdgcn_mbcnt_hi((unsigned)(m3 >> 32),
            __builtin_amdgcn_mbcnt_lo((unsigned)m3, below));

    const int n = __popcll(m0) + __popcll(m1) + __popcll(m2) + __popcll(m3);

    // 3) Scatter nonzeros into this wave's private LDS slice.
    int pos = below;
    int* const c = c_sh[wave];
    #pragma unroll
    for (int j = 0; j < 4; ++j) {
        if (vals[j] != 0) c[pos++] = vals[j];
    }

    // Wave-private slice: only THIS wave's DS writes must complete before
    // its reads. No block barrier required.
    __asm__ volatile("s_waitcnt lgkmcnt(0)" ::: "memory");

    // 4) Lane l evaluates compacted positions [4l, 4l+4).
    const int base = lane * 4;
    const int4 q = ((const int4*)c)[lane];   // b128, stride-16B: conflict-free
    // c[base+4], c[base+5] live in the next lane's q.x, q.y. (Lane 63's
    // results are garbage but provably never used: guards need n > 256.)
    const int e0 = __shfl_down(q.x, 1, 64);
    const int e1 = __shfl_down(q.y, 1, 64);
    const int a0[6] = { q.x, q.y, q.z, q.w, e0, e1 };

    // Packed counters: rep | inc<<8 | dec<<16 | per<<24.
    // Each field's wave-total <= 255, so no cross-field carries.
    int packed = 0;
    #pragma unroll
    for (int j = 0; j < 4; ++j) {
        const int i  = base + j;
        const int a  = a0[j];
        const int b  = a0[j + 1];
        const int c2 = a0[j + 2];
        if (i < n - 1) {
            packed += (a == b) ? 1          : 0;
            packed += (b >  a) ? (1 << 8)   : 0;
            packed += (b <  a) ? (1 << 16)  : 0;
            if (i < n - 2) packed += (a == c2) ? (1 << 24) : 0;
        }
    }

    // 5) Wave reduction on the VALU pipe via DPP; total lands in lane 63.
    int vsum = packed;
    int t;
    t = __builtin_amdgcn_update_dpp(0, vsum, 0x111, 0xF, 0xF, true); vsum += t; // row_shr:1
    t = __builtin_amdgcn_update_dpp(0, vsum, 0x112, 0xF, 0xF, true); vsum += t; // row_shr:2
    t = __builtin_amdgcn_update_dpp(0, vsum, 0x114, 0xF, 0xE, true); vsum += t; // row_shr:4
    t = __builtin_amdgcn_update_dpp(0, vsum, 0x118, 0xF, 0xC, true); vsum += t; // row_shr:8
    t = __builtin_amdgcn_update_dpp(0, vsum, 0x142, 0xA, 0xF, true); vsum += t; // row_bcast:15
    t = __builtin_amdgcn_update_dpp(0, vsum, 0x143, 0xC, 0xF, true); vsum += t; // row_bcast:31

    // 6) Lane 63 holds the totals; write the 4 features.
    if (lane == 63 && valid_row) {
        const int rep =  vsum        & 0xFF;
        const int inc = (vsum >> 8)  & 0xFF;
        const int dec = (vsum >> 16) & 0xFF;
        const int per = (vsum >> 24) & 0xFF;
        float4 o = make_float4(0.f, 0.f, 0.f, 0.f);
        if (n > 1) {
            const float d1 = (float)(n - 1);
            o.x = (float)rep / d1;
            o.y = (float)inc / d1;
            o.z = (float)dec / d1;
            if (n >= 4) o.w = (float)per / (float)(n - 2);
        }
        ((float4*)out)[row] = o;
    }
}

extern "C" void kernel_launch(void* const* d_in, const int* in_sizes, int n_in,
                              void* d_out, int out_size, void* d_ws, size_t ws_size,
                              hipStream_t stream) {
    const int* x  = (const int*)d_in[0];
    float*    out = (float*)d_out;
    const int rows   = in_sizes[0] / L_SEQ;
    const int blocks = (rows + WPB - 1) / WPB;
    pattern_kernel<<<dim3(blocks), dim3(256), 0, stream>>>(x, out, rows);
}